// Round 4
// baseline (1119.679 us; speedup 1.0000x reference)
//
#include <hip/hip_runtime.h>
#include <hip/hip_bf16.h>

#define BB 512
#define SS 1024
#define NI 20
#define HH 64
#define NG 256  // 4*H
#define MB 16   // batches per block
#define PAD 72

typedef unsigned short u16;
typedef unsigned int u32;
typedef unsigned long long u64;
typedef _Float16 f16;
typedef f16 f16x8 __attribute__((ext_vector_type(8)));
typedef float f32x4 __attribute__((ext_vector_type(4)));

__device__ __forceinline__ float bf2f(u16 b) { return __uint_as_float(((u32)b) << 16); }
// mode==1: data is bf16; mode==0: data is fp32
__device__ __forceinline__ float ldw(const void* p, int idx, int mode) {
  return mode ? bf2f(((const u16*)p)[idx]) : ((const float*)p)[idx];
}
__device__ __forceinline__ float frcp(float x) { return __builtin_amdgcn_rcpf(x); }
__device__ __forceinline__ float sigf(float x) { return frcp(1.f + __expf(-x)); }
__device__ __forceinline__ float tanhf_(float x) {
  float e = __expf(2.f * x);           // overflow -> inf -> rcp -> 0 -> +1; underflow -> 0 -> -1
  return 1.f - 2.f * frcp(e + 1.f);
}

// one-hot A-chunk for k in [8q, 8q+8), f16 1.0 at k==tok, plus constant-1 at k==20 (bias slot).
// tok==-1 (padding) -> only the bias slot. ~12 VALU ops via 64-bit shift.
__device__ __forceinline__ f16x8 onehot21(int tok, int q) {
  int rel = tok - 8 * q;
  u64 t64 = 0x3C00ull << ((rel << 4) & 63);
  u64 lo = ((u32)rel < 4u) ? t64 : 0ull;
  u64 hi = ((u32)(rel - 4) < 4u) ? t64 : 0ull;
  if (q == 2) hi |= 0x3C00ull;  // k=20: constant 1.0 (bias row in B); lane-uniform per quad
  union { u64 u[2]; f16x8 v; } un;
  un.u[0] = lo; un.u[1] = hi;
  return un.v;
}

// ---- dtype probe (parallel): read b_f (256 elems) as bf16; fp32 data shows wild exponents ----
__global__ void probe_kernel(const void* bvec, int* mode) {
  __shared__ int bad;
  int t = threadIdx.x;
  if (t == 0) bad = 0;
  __syncthreads();
  float v = bf2f(((const u16*)bvec)[t]);
  if (!(fabsf(v) < 1000.0f)) atomicOr(&bad, 1);
  __syncthreads();
  if (t == 0) *mode = bad ? 0 : 1;
}

// ---- tokens + lengths from one-hot input ----
__global__ void tok_kernel(const void* in1, const int* mode_p, short* toks, int* lens) {
  int b = blockIdx.x;
  int t = threadIdx.x;
  int mode = *mode_p;
  int cnt = 0;
  if (mode) {
    for (int q = 0; q < 4; ++q) {
      int s = t + q * 256;
      const u32* r = (const u32*)in1 + (size_t)(b * SS + s) * 10;  // 2 bf16 per u32
      int tok = -1;
#pragma unroll
      for (int w = 0; w < 10; ++w) {
        u32 u = r[w];
        if (u & 0xFFFFu) tok = 2 * w;
        if (u >> 16)     tok = 2 * w + 1;
      }
      toks[b * SS + s] = (short)tok;
      cnt += (tok >= 0);
    }
  } else {
    for (int q = 0; q < 4; ++q) {
      int s = t + q * 256;
      const float4* r = (const float4*)((const float*)in1 + (size_t)(b * SS + s) * 20);
      int tok = -1;
#pragma unroll
      for (int w = 0; w < 5; ++w) {
        float4 u = r[w];
        if (u.x != 0.f) tok = 4 * w;
        if (u.y != 0.f) tok = 4 * w + 1;
        if (u.z != 0.f) tok = 4 * w + 2;
        if (u.w != 0.f) tok = 4 * w + 3;
      }
      toks[b * SS + s] = (short)tok;
      cnt += (tok >= 0);
    }
  }
  __shared__ int red[256];
  red[t] = cnt;
  __syncthreads();
  for (int stp = 128; stp > 0; stp >>= 1) {
    if (t < stp) red[t] += red[t + stp];
    __syncthreads();
  }
  if (t == 0) lens[b] = red[0];
}

// ---- BiLSTM via MFMA, two chains (fwd+bwd) interleaved per wave ----
// Block = 16-batch tile, BOTH directions. 4 waves; wave w owns units 16w..16w+15 (all 4
// gate types -> in-lane activations). Per barrier-period each chain advances one step;
// the two chains' issue fills each other's latency stalls (1 wave/SIMD, issue-bound).
// Bias rides in B at K-slot 20 (A has constant 1.0 there) -> zero C-init, hoisted.
__global__ __launch_bounds__(256)
void lstm_kernel(const void* Wih_f, const void* Whh_f, const void* b_f,
                 const void* Wih_b, const void* Whh_b, const void* b_b,
                 const int* mode_p, const short* toks, float* hout) {
  int bx = blockIdx.x;          // 0..31
  int b0 = bx * MB;
  int t = threadIdx.x;
  int w = t >> 6, lane = t & 63, l = lane & 15, q = lane >> 4;
  int mode = *mode_p;

  __shared__ __align__(16) f16 hb[2][2][MB][PAD];  // [chain][p][batch][unit(+pad)]
  __shared__ short tok_pad[MB + SS * MB + MB];     // front/back pad for s+-1 prefetch overrun
  short* tok_s = tok_pad + MB;

  for (int idx = t; idx < MB * SS; idx += 256) {
    int m = idx >> 10, pos = idx & (SS - 1);
    tok_s[pos * MB + m] = toks[(size_t)(b0 + m) * SS + pos];
  }
  if (t < MB) { tok_pad[t] = 0; tok_pad[MB + SS * MB + t] = 0; }
  for (int idx = t; idx < 2 * 2 * MB * PAD; idx += 256)
    ((f16*)hb)[idx] = (f16)0.f;

  // B fragments: n=lane&15 -> gate col, k=q*8+j. kc0/1: W_hh; kc2: W_ih cols + bias at k=20.
  f16x8 BfF[4][3], BfB[4][3];
#pragma unroll
  for (int tt = 0; tt < 4; ++tt) {
    int g = 64 * tt + 16 * w + l;
#pragma unroll
    for (int kc = 0; kc < 2; ++kc) {
      f16x8 vF, vB;
#pragma unroll
      for (int j = 0; j < 8; ++j) {
        vF[j] = (f16)ldw(Whh_f, g * HH + kc * 32 + q * 8 + j, mode);
        vB[j] = (f16)ldw(Whh_b, g * HH + kc * 32 + q * 8 + j, mode);
      }
      BfF[tt][kc] = vF; BfB[tt][kc] = vB;
    }
    f16x8 v2F, v2B;
#pragma unroll
    for (int j = 0; j < 8; ++j) {
      int i = q * 8 + j;
      float fF = 0.f, fB = 0.f;
      if (i < NI)       { fF = ldw(Wih_f, g * NI + i, mode); fB = ldw(Wih_b, g * NI + i, mode); }
      else if (i == NI) { fF = ldw(b_f, g, mode);            fB = ldw(b_b, g, mode); }
      v2F[j] = (f16)fF; v2B[j] = (f16)fB;
    }
    BfF[tt][2] = v2F; BfB[tt][2] = v2B;
  }
  __syncthreads();

  float cF[4] = {0, 0, 0, 0}, cB[4] = {0, 0, 0, 0};
  float hF[4] = {0, 0, 0, 0}, hB[4] = {0, 0, 0, 0};
  const f32x4 z4 = {0.f, 0.f, 0.f, 0.f};
  f32x4 accAF[4], accAB[4];
  {  // prologue: input projection (+bias) for s=0, both chains
    f16x8 aF = onehot21((int)tok_s[0 * MB + l], q);
    f16x8 aB = onehot21((int)tok_s[(SS - 1) * MB + l], q);
#pragma unroll
    for (int tt = 0; tt < 4; ++tt) {
      accAF[tt] = __builtin_amdgcn_mfma_f32_16x16x32_f16(aF, BfF[tt][2], z4, 0, 0, 0);
      accAB[tt] = __builtin_amdgcn_mfma_f32_16x16x32_f16(aB, BfB[tt][2], z4, 0, 0, 0);
    }
  }
  int jj = 16 * w + l;

#pragma unroll 2
  for (int s = 0; s < SS; ++s) {
    int p = s & 1;
    // critical path: h fragments for both chains (A[m=batch l][k=q*8+j])
    f16x8 aF0 = *(const f16x8*)&hb[0][p][l][q * 8];
    f16x8 aF1 = *(const f16x8*)&hb[0][p][l][32 + q * 8];
    f16x8 aB0 = *(const f16x8*)&hb[1][p][l][q * 8];
    f16x8 aB1 = *(const f16x8*)&hb[1][p][l][32 + q * 8];
    // off-path: tokens for step s+1 (pad-protected at both ends)
    int tkF = (int)tok_s[(s + 1) * MB + l];
    int tkB = (int)tok_s[(SS - 2 - s) * MB + l];

    f32x4 gF[4], gB[4];
#pragma unroll
    for (int tt = 0; tt < 4; ++tt) {
      gF[tt] = __builtin_amdgcn_mfma_f32_16x16x32_f16(aF0, BfF[tt][0], accAF[tt], 0, 0, 0);
      gB[tt] = __builtin_amdgcn_mfma_f32_16x16x32_f16(aB0, BfB[tt][0], accAB[tt], 0, 0, 0);
    }
#pragma unroll
    for (int tt = 0; tt < 4; ++tt) {
      gF[tt] = __builtin_amdgcn_mfma_f32_16x16x32_f16(aF1, BfF[tt][1], gF[tt], 0, 0, 0);
      gB[tt] = __builtin_amdgcn_mfma_f32_16x16x32_f16(aB1, BfB[tt][1], gB[tt], 0, 0, 0);
    }
    // off-path: input projection (+bias) for s+1, both chains
    {
      f16x8 a2F = onehot21(tkF, q), a2B = onehot21(tkB, q);
#pragma unroll
      for (int tt = 0; tt < 4; ++tt) {
        accAF[tt] = __builtin_amdgcn_mfma_f32_16x16x32_f16(a2F, BfF[tt][2], z4, 0, 0, 0);
        accAB[tt] = __builtin_amdgcn_mfma_f32_16x16x32_f16(a2B, BfB[tt][2], z4, 0, 0, 0);
      }
    }
    // activations, chains interleaved per row: batch m=4q+r, unit jj, gates i,f,g,o in-lane
#pragma unroll
    for (int r = 0; r < 4; ++r) {
      {
        float cv = sigf(gF[1][r]) * cF[r] + sigf(gF[0][r]) * tanhf_(gF[2][r]);
        cF[r] = cv;
        float hv = sigf(gF[3][r]) * tanhf_(cv);
        hF[r] = hv;
        hb[0][p ^ 1][4 * q + r][jj] = (f16)hv;
      }
      {
        float cv = sigf(gB[1][r]) * cB[r] + sigf(gB[0][r]) * tanhf_(gB[2][r]);
        cB[r] = cv;
        float hv = sigf(gB[3][r]) * tanhf_(cv);
        hB[r] = hv;
        hb[1][p ^ 1][4 * q + r][jj] = (f16)hv;
      }
    }
    __syncthreads();
  }
#pragma unroll
  for (int r = 0; r < 4; ++r) {
    hout[(b0 + 4 * q + r) * 128 + jj]      = hF[r];
    hout[(b0 + 4 * q + r) * 128 + 64 + jj] = hB[r];
  }
}

// ---- conv path + FC head + softmax; 1 block = 1 batch, 256 threads ----
__global__ void head_kernel(const void* conv1_w, const void* conv2_w, const void* conv2_b,
                            const void* fc1_w, const void* fc1_b,
                            const void* fc2_w, const void* fc2_b,
                            const int* mode_p, const short* toks, const int* lens,
                            const float* hout, void* out) {
  int b = blockIdx.x;
  int t = threadIdx.x;  // 256 threads
  int mode = *mode_p;
  __shared__ float c1w[400];
  __shared__ short tok_s[SS];
  __shared__ float pav[2][80];
  __shared__ float avg[80];
  __shared__ float merged[228];
  __shared__ float fc1v[64];

  for (int i = t; i < 400; i += 256) c1w[i] = ldw(conv1_w, i, mode);
  for (int s = t; s < SS; s += 256) tok_s[s] = toks[b * SS + s];
  __syncthreads();

  int len = lens[b];
  int bw = len >> 2;
  if (t < 160) {
    int half = t / 80;
    int u = t - half * 80;
    int k = u / 20, cc = u % 20;
    int start = k * bw, mid = k * bw + (bw >> 1), end = (k + 1) * bw;
    int s0 = half ? mid : start;
    int s1 = half ? end : mid;
    float sum = 0.f;
    for (int s = s0; s < s1; ++s) {
      // faithful torch reshape: c1r[b,s,cc] lives at flat f = s*20+cc of the [20,1024] map
      int f = s * 20 + cc;
      int ch = f >> 10;
      int pos = f & 1023;
      int tk = tok_s[pos];
      if (tk >= 0) sum += c1w[ch * 20 + tk];  // pos >= len -> zero row -> contributes 0
    }
    pav[half][u] = sum;
  }
  __syncthreads();
  if (t < 80) avg[t] = (pav[0][t] + pav[1][t]) / (float)bw;
  __syncthreads();

  if (t < 128) merged[t] = hout[b * 128 + t];  // [h_fw | h_bw]
  if (t >= 128 && t < 228) {
    int o = t - 128;
    float dot = ldw(conv2_b, o, mode);
#pragma unroll
    for (int q = 0; q < 80; ++q)
      dot += avg[q] * ldw(conv2_w, o * 80 + q, mode);
    merged[t] = dot > 0.f ? dot : 0.f;  // relu
  }
  __syncthreads();

  if (t < 64) {
    float v = ldw(fc1_b, t, mode);
    for (int m = 0; m < 228; ++m)
      v += merged[m] * ldw(fc1_w, t * 228 + m, mode);
    fc1v[t] = v;   // no activation on fc1 per reference
  }
  __syncthreads();

  if (t == 0) {
    float x0 = ldw(fc2_b, 0, mode), x1 = ldw(fc2_b, 1, mode);
    for (int m = 0; m < 64; ++m) {
      x0 += fc1v[m] * ldw(fc2_w, m, mode);
      x1 += fc1v[m] * ldw(fc2_w, 64 + m, mode);
    }
    float mx = fmaxf(x0, x1);
    float e0 = __expf(x0 - mx), e1 = __expf(x1 - mx);
    float inv = 1.f / (e0 + e1);
    if (mode) {
      ((__hip_bfloat16*)out)[b * 2 + 0] = __float2bfloat16(e0 * inv);
      ((__hip_bfloat16*)out)[b * 2 + 1] = __float2bfloat16(e1 * inv);
    } else {
      ((float*)out)[b * 2 + 0] = e0 * inv;
      ((float*)out)[b * 2 + 1] = e1 * inv;
    }
  }
}

extern "C" void kernel_launch(void* const* d_in, const int* in_sizes, int n_in,
                              void* d_out, int out_size, void* d_ws, size_t ws_size,
                              hipStream_t stream) {
  (void)in_sizes; (void)n_in; (void)out_size; (void)ws_size;
  char* ws = (char*)d_ws;
  int*   mode_p = (int*)ws;                                   // 4 B
  int*   lens   = (int*)(ws + 256);                           // 2 KB
  short* toks   = (short*)(ws + 256 + 2048);                  // 1 MB
  float* hout   = (float*)(ws + 256 + 2048 + (size_t)BB * SS * sizeof(short)); // 256 KB

  probe_kernel<<<1, 256, 0, stream>>>(d_in[3], mode_p);
  tok_kernel<<<BB, 256, 0, stream>>>(d_in[0], mode_p, toks, lens);
  lstm_kernel<<<32, 256, 0, stream>>>(d_in[1], d_in[2], d_in[3],
                                      d_in[4], d_in[5], d_in[6],
                                      mode_p, toks, hout);
  head_kernel<<<BB, 256, 0, stream>>>(d_in[7], d_in[8], d_in[9],
                                      d_in[10], d_in[11], d_in[12], d_in[13],
                                      mode_p, toks, lens, hout, d_out);
}

// Round 5
// 659.910 us; speedup vs baseline: 1.6967x; 1.6967x over previous
//
#include <hip/hip_runtime.h>
#include <hip/hip_bf16.h>

#define BB 512
#define SS 1024
#define NI 20
#define HH 64
#define NG 256  // 4*H
#define MB 16   // batches per block
#define PAD 72

typedef unsigned short u16;
typedef unsigned int u32;
typedef unsigned long long u64;
typedef _Float16 f16;
typedef f16 f16x8 __attribute__((ext_vector_type(8)));
typedef float f32x4 __attribute__((ext_vector_type(4)));

#define LOG2E 1.4426950408889634f

__device__ __forceinline__ float bf2f(u16 b) { return __uint_as_float(((u32)b) << 16); }
// mode==1: data is bf16; mode==0: data is fp32
__device__ __forceinline__ float ldw(const void* p, int idx, int mode) {
  return mode ? bf2f(((const u16*)p)[idx]) : ((const float*)p)[idx];
}
__device__ __forceinline__ float frcp(float x) { return __builtin_amdgcn_rcpf(x); }
__device__ __forceinline__ float fexp2(float x) { return __builtin_amdgcn_exp2f(x); }
__device__ __forceinline__ float sigf(float x) { return frcp(1.f + fexp2(-LOG2E * x)); }
__device__ __forceinline__ float tanhf_(float x) {
  float e = fexp2(2.f * LOG2E * x);
  return 1.f - 2.f * frcp(e + 1.f);
}

// one-hot A-chunk for k in [8q, 8q+8), f16 1.0 at k==tok, plus constant-1 at k==20 (bias slot).
// tok==-1 (padding) -> only the bias slot. ~12 VALU ops via 64-bit shift. [verified r4: absmax 0]
__device__ __forceinline__ f16x8 onehot21(int tok, int q) {
  int rel = tok - 8 * q;
  u64 t64 = 0x3C00ull << ((rel << 4) & 63);
  u64 lo = ((u32)rel < 4u) ? t64 : 0ull;
  u64 hi = ((u32)(rel - 4) < 4u) ? t64 : 0ull;
  if (q == 2) hi |= 0x3C00ull;  // k=20: constant 1.0 (bias row in B); lane-uniform per quad
  union { u64 u[2]; f16x8 v; } un;
  un.u[0] = lo; un.u[1] = hi;
  return un.v;
}

// ---- dtype probe (parallel): read b_f (256 elems) as bf16; fp32 data shows wild exponents ----
__global__ void probe_kernel(const void* bvec, int* mode) {
  __shared__ int bad;
  int t = threadIdx.x;
  if (t == 0) bad = 0;
  __syncthreads();
  float v = bf2f(((const u16*)bvec)[t]);
  if (!(fabsf(v) < 1000.0f)) atomicOr(&bad, 1);
  __syncthreads();
  if (t == 0) *mode = bad ? 0 : 1;
}

// ---- tokens + lengths from one-hot input; LDS-staged for coalesced HBM reads ----
__global__ void tok_kernel(const void* in1, const int* mode_p, short* toks, int* lens) {
  int b = blockIdx.x;
  int t = threadIdx.x;
  int mode = *mode_p;
  __shared__ __align__(16) float stage[256 * 20];  // 20 KB: 256 rows per chunk
  __shared__ int red[256];
  int cnt = 0;
  if (mode) {
    u32* st = (u32*)stage;
    for (int k0 = 0; k0 < 4; ++k0) {
      const u32* src = (const u32*)in1 + ((size_t)b * SS + k0 * 256) * 10;
#pragma unroll
      for (int i = 0; i < 10; ++i) st[t + i * 256] = src[t + i * 256];  // coalesced
      __syncthreads();
      const u32* row = st + t * 10;
      int tok = -1;
#pragma unroll
      for (int w = 0; w < 10; ++w) {
        u32 u = row[w];
        if (u & 0xFFFFu) tok = 2 * w;
        if (u >> 16)     tok = 2 * w + 1;
      }
      toks[b * SS + k0 * 256 + t] = (short)tok;
      cnt += (tok >= 0);
      __syncthreads();
    }
  } else {
    float4* st = (float4*)stage;
    for (int k0 = 0; k0 < 4; ++k0) {
      const float4* src = (const float4*)((const float*)in1 + ((size_t)b * SS + k0 * 256) * 20);
#pragma unroll
      for (int i = 0; i < 5; ++i) st[t + i * 256] = src[t + i * 256];  // coalesced 16B/lane
      __syncthreads();
      const float* row = stage + t * 20;
      int tok = -1;
#pragma unroll
      for (int w = 0; w < 20; ++w)
        if (row[w] != 0.f) tok = w;
      toks[b * SS + k0 * 256 + t] = (short)tok;
      cnt += (tok >= 0);
      __syncthreads();
    }
  }
  red[t] = cnt;
  __syncthreads();
  for (int stp = 128; stp > 0; stp >>= 1) {
    if (t < stp) red[t] += red[t + stp];
    __syncthreads();
  }
  if (t == 0) lens[b] = red[0];
}

// ---- BiLSTM via MFMA. Block = (dir, 16-batch tile); wave w owns units 16w..16w+15,
// all 4 gate types -> in-lane activations. Issue-bound (r4 lesson): so minimize issue.
// Weights prescaled: i,f,o rows by -log2e, g rows by +2log2e -> gates arrive as exp2 args.
// Activation: 5 exp2 + 2 rcp per cell (divisions folded via common denominators).
__global__ __launch_bounds__(256)
void lstm_kernel(const void* Wih_f, const void* Whh_f, const void* b_f,
                 const void* Wih_b, const void* Whh_b, const void* b_b,
                 const int* mode_p, const short* toks, float* hout) {
  int bx = blockIdx.x;
  int dir = bx >> 5;
  int b0 = (bx & 31) * MB;
  int t = threadIdx.x;
  int w = t >> 6, lane = t & 63, l = lane & 15, q = lane >> 4;
  int mode = *mode_p;
  const void* Wih = dir ? Wih_b : Wih_f;
  const void* Whh = dir ? Whh_b : Whh_f;
  const void* bv  = dir ? b_b   : b_f;

  __shared__ __align__(16) f16 hbuf[2][MB][PAD];  // stride 72 f16 = 144B; 2-way bank alias = free
  __shared__ short tok_s[SS * MB];                // [pos][m]

  for (int idx = t; idx < MB * SS; idx += 256) {
    int m = idx >> 10, pos = idx & (SS - 1);
    tok_s[pos * MB + m] = toks[(size_t)(b0 + m) * SS + pos];
  }
  for (int idx = t; idx < 2 * MB * PAD; idx += 256)
    ((f16*)hbuf)[idx] = (f16)0.f;

  // B fragments: n=lane&15 -> gate col, k=q*8+j. kc0/1: W_hh; kc2: W_ih cols + bias at k=20.
  // Row prescale: tt in {i,f,o} -> -log2e (so exp2(acc)=e^-gate); tt==2 (g) -> +2log2e.
  f16x8 Bf[4][3];
#pragma unroll
  for (int tt = 0; tt < 4; ++tt) {
    float scl = (tt == 2) ? (2.f * LOG2E) : (-LOG2E);
    int g = 64 * tt + 16 * w + l;
#pragma unroll
    for (int kc = 0; kc < 2; ++kc) {
      f16x8 v;
#pragma unroll
      for (int j = 0; j < 8; ++j)
        v[j] = (f16)(scl * ldw(Whh, g * HH + kc * 32 + q * 8 + j, mode));
      Bf[tt][kc] = v;
    }
    f16x8 v2;
#pragma unroll
    for (int j = 0; j < 8; ++j) {
      int i = q * 8 + j;
      float f = 0.f;
      if (i < NI)       f = ldw(Wih, g * NI + i, mode);
      else if (i == NI) f = ldw(bv, g, mode);
      v2[j] = (f16)(scl * f);
    }
    Bf[tt][2] = v2;
  }
  __syncthreads();

  float c_st[4] = {0.f, 0.f, 0.f, 0.f};
  float hlast[4] = {0.f, 0.f, 0.f, 0.f};
  int jj = 16 * w + l;
  const f32x4 z4 = {0.f, 0.f, 0.f, 0.f};

  // prologue: input projection (+bias) for s=0
  f32x4 accA[4];
  {
    int pos0 = dir ? (SS - 1) : 0;
    f16x8 a2 = onehot21((int)tok_s[pos0 * MB + l], q);
#pragma unroll
    for (int tt = 0; tt < 4; ++tt)
      accA[tt] = __builtin_amdgcn_mfma_f32_16x16x32_f16(a2, Bf[tt][2], z4, 0, 0, 0);
  }

#pragma unroll 2
  for (int s = 0; s < SS; ++s) {
    int p = s & 1;
    // critical path: h fragments (A[m=batch l][k=q*8+j])
    f16x8 a0 = *(const f16x8*)&hbuf[p][l][q * 8];
    f16x8 a1 = *(const f16x8*)&hbuf[p][l][32 + q * 8];
    // off-path: token for step s+1 (mask-wrapped; wrapped value unused)
    int posn = (dir ? (SS - 2 - s) : (s + 1)) & (SS - 1);
    int tkn = (int)tok_s[posn * MB + l];

    f32x4 acc[4];
#pragma unroll
    for (int tt = 0; tt < 4; ++tt)
      acc[tt] = __builtin_amdgcn_mfma_f32_16x16x32_f16(a0, Bf[tt][0], accA[tt], 0, 0, 0);
#pragma unroll
    for (int tt = 0; tt < 4; ++tt)
      acc[tt] = __builtin_amdgcn_mfma_f32_16x16x32_f16(a1, Bf[tt][1], acc[tt], 0, 0, 0);

    // off-path: input projection (+bias) for s+1
    {
      f16x8 a2 = onehot21(tkn, q);
#pragma unroll
      for (int tt = 0; tt < 4; ++tt)
        accA[tt] = __builtin_amdgcn_mfma_f32_16x16x32_f16(a2, Bf[tt][2], z4, 0, 0, 0);
    }

    // activations: batch m=4q+r, unit jj; gates prescaled as exp2 args.
    // Ei=e^-i, Ef=e^-f, Eo=e^-o, G=e^2g:
    //   c' = [c(1+Ei)(G+1) + (G-1)(1+Ef)] / [(1+Ef)(1+Ei)(G+1)]     (sig(f)c + sig(i)tanh(g))
    //   C  = exp2(2*log2e*c');  h = (C-1)/[(1+Eo)(C+1)]             (sig(o)tanh(c'))
#pragma unroll
    for (int r = 0; r < 4; ++r) {
      float Ei = fexp2(acc[0][r]);
      float Ef = fexp2(acc[1][r]);
      float G  = fexp2(acc[2][r]);
      float Eo = fexp2(acc[3][r]);
      float Ei1 = Ei + 1.f, Ef1 = Ef + 1.f, G1 = G + 1.f, Gm = G - 1.f;
      float t1 = Ei1 * G1;
      float num = fmaf(c_st[r], t1, Gm * Ef1);
      float cv = num * frcp(t1 * Ef1);
      c_st[r] = cv;
      float C = fexp2((2.f * LOG2E) * cv);
      float hv = (C - 1.f) * frcp((Eo + 1.f) * (C + 1.f));
      hlast[r] = hv;
      hbuf[p ^ 1][4 * q + r][jj] = (f16)hv;
    }
    __syncthreads();
  }
#pragma unroll
  for (int r = 0; r < 4; ++r)
    hout[(b0 + 4 * q + r) * 128 + dir * 64 + jj] = hlast[r];
}

// ---- conv path + FC head + softmax; 1 block = 1 batch, 256 threads ----
__global__ void head_kernel(const void* conv1_w, const void* conv2_w, const void* conv2_b,
                            const void* fc1_w, const void* fc1_b,
                            const void* fc2_w, const void* fc2_b,
                            const int* mode_p, const short* toks, const int* lens,
                            const float* hout, void* out) {
  int b = blockIdx.x;
  int t = threadIdx.x;  // 256 threads
  int mode = *mode_p;
  __shared__ float c1w[400];
  __shared__ short tok_s[SS];
  __shared__ float pav[2][80];
  __shared__ float avg[80];
  __shared__ float merged[228];
  __shared__ float fc1v[64];

  for (int i = t; i < 400; i += 256) c1w[i] = ldw(conv1_w, i, mode);
  for (int s = t; s < SS; s += 256) tok_s[s] = toks[b * SS + s];
  __syncthreads();

  int len = lens[b];
  int bw = len >> 2;
  if (t < 160) {
    int half = t / 80;
    int u = t - half * 80;
    int k = u / 20, cc = u % 20;
    int start = k * bw, mid = k * bw + (bw >> 1), end = (k + 1) * bw;
    int s0 = half ? mid : start;
    int s1 = half ? end : mid;
    float sum = 0.f;
    for (int s = s0; s < s1; ++s) {
      // faithful torch reshape: c1r[b,s,cc] lives at flat f = s*20+cc of the [20,1024] map
      int f = s * 20 + cc;
      int ch = f >> 10;
      int pos = f & 1023;
      int tk = tok_s[pos];
      if (tk >= 0) sum += c1w[ch * 20 + tk];  // pos >= len -> zero row -> contributes 0
    }
    pav[half][u] = sum;
  }
  __syncthreads();
  if (t < 80) avg[t] = (pav[0][t] + pav[1][t]) / (float)bw;
  __syncthreads();

  if (t < 128) merged[t] = hout[b * 128 + t];  // [h_fw | h_bw]
  if (t >= 128 && t < 228) {
    int o = t - 128;
    float dot = ldw(conv2_b, o, mode);
#pragma unroll
    for (int q = 0; q < 80; ++q)
      dot += avg[q] * ldw(conv2_w, o * 80 + q, mode);
    merged[t] = dot > 0.f ? dot : 0.f;  // relu
  }
  __syncthreads();

  if (t < 64) {
    float v = ldw(fc1_b, t, mode);
    for (int m = 0; m < 228; ++m)
      v += merged[m] * ldw(fc1_w, t * 228 + m, mode);
    fc1v[t] = v;   // no activation on fc1 per reference
  }
  __syncthreads();

  if (t == 0) {
    float x0 = ldw(fc2_b, 0, mode), x1 = ldw(fc2_b, 1, mode);
    for (int m = 0; m < 64; ++m) {
      x0 += fc1v[m] * ldw(fc2_w, m, mode);
      x1 += fc1v[m] * ldw(fc2_w, 64 + m, mode);
    }
    float mx = fmaxf(x0, x1);
    float e0 = fexp2(LOG2E * (x0 - mx)), e1 = fexp2(LOG2E * (x1 - mx));
    float inv = 1.f / (e0 + e1);
    if (mode) {
      ((__hip_bfloat16*)out)[b * 2 + 0] = __float2bfloat16(e0 * inv);
      ((__hip_bfloat16*)out)[b * 2 + 1] = __float2bfloat16(e1 * inv);
    } else {
      ((float*)out)[b * 2 + 0] = e0 * inv;
      ((float*)out)[b * 2 + 1] = e1 * inv;
    }
  }
}

extern "C" void kernel_launch(void* const* d_in, const int* in_sizes, int n_in,
                              void* d_out, int out_size, void* d_ws, size_t ws_size,
                              hipStream_t stream) {
  (void)in_sizes; (void)n_in; (void)out_size; (void)ws_size;
  char* ws = (char*)d_ws;
  int*   mode_p = (int*)ws;                                   // 4 B
  int*   lens   = (int*)(ws + 256);                           // 2 KB
  short* toks   = (short*)(ws + 256 + 2048);                  // 1 MB
  float* hout   = (float*)(ws + 256 + 2048 + (size_t)BB * SS * sizeof(short)); // 256 KB

  probe_kernel<<<1, 256, 0, stream>>>(d_in[3], mode_p);
  tok_kernel<<<BB, 256, 0, stream>>>(d_in[0], mode_p, toks, lens);
  lstm_kernel<<<64, 256, 0, stream>>>(d_in[1], d_in[2], d_in[3],
                                      d_in[4], d_in[5], d_in[6],
                                      mode_p, toks, hout);
  head_kernel<<<BB, 256, 0, stream>>>(d_in[7], d_in[8], d_in[9],
                                      d_in[10], d_in[11], d_in[12], d_in[13],
                                      mode_p, toks, lens, hout, d_out);
}

// Round 6
// 476.225 us; speedup vs baseline: 2.3512x; 1.3857x over previous
//
#include <hip/hip_runtime.h>
#include <hip/hip_bf16.h>

#define BB 512
#define SS 1024
#define NI 20
#define HH 64
#define NG 256  // 4*H
#define MB4 4   // batch-dirs per block (1 cell per lane)
#define PAD 72

typedef unsigned short u16;
typedef unsigned int u32;
typedef unsigned long long u64;
typedef _Float16 f16;
typedef f16 f16x8 __attribute__((ext_vector_type(8)));
typedef float f32x4 __attribute__((ext_vector_type(4)));

#define LOG2E 1.4426950408889634f

__device__ __forceinline__ float bf2f(u16 b) { return __uint_as_float(((u32)b) << 16); }
// mode==1: data is bf16; mode==0: data is fp32
__device__ __forceinline__ float ldw(const void* p, int idx, int mode) {
  return mode ? bf2f(((const u16*)p)[idx]) : ((const float*)p)[idx];
}
__device__ __forceinline__ float frcp(float x) { return __builtin_amdgcn_rcpf(x); }
__device__ __forceinline__ float fexp2(float x) { return __builtin_amdgcn_exp2f(x); }

// one-hot A-chunk for k in [8q, 8q+8), f16 1.0 at k==tok, plus constant-1 at k==20 (bias slot).
// tok==-1 (padding) -> only the bias slot. [verified r4/r5: absmax 0]
__device__ __forceinline__ f16x8 onehot21(int tok, int q) {
  int rel = tok - 8 * q;
  u64 t64 = 0x3C00ull << ((rel << 4) & 63);
  u64 lo = ((u32)rel < 4u) ? t64 : 0ull;
  u64 hi = ((u32)(rel - 4) < 4u) ? t64 : 0ull;
  if (q == 2) hi |= 0x3C00ull;  // k=20: constant 1.0 (bias row in B)
  union { u64 u[2]; f16x8 v; } un;
  un.u[0] = lo; un.u[1] = hi;
  return un.v;
}

// ---- dtype probe (parallel): read b_f (256 elems) as bf16; fp32 data shows wild exponents ----
__global__ void probe_kernel(const void* bvec, int* mode) {
  __shared__ int bad;
  int t = threadIdx.x;
  if (t == 0) bad = 0;
  __syncthreads();
  float v = bf2f(((const u16*)bvec)[t]);
  if (!(fabsf(v) < 1000.0f)) atomicOr(&bad, 1);
  __syncthreads();
  if (t == 0) *mode = bad ? 0 : 1;
}

// ---- tokens + lengths from one-hot input; LDS-staged for coalesced HBM reads ----
__global__ void tok_kernel(const void* in1, const int* mode_p, short* toks, int* lens) {
  int b = blockIdx.x;
  int t = threadIdx.x;
  int mode = *mode_p;
  __shared__ __align__(16) float stage[256 * 20];  // 20 KB
  __shared__ int red[256];
  int cnt = 0;
  if (mode) {
    u32* st = (u32*)stage;
    for (int k0 = 0; k0 < 4; ++k0) {
      const u32* src = (const u32*)in1 + ((size_t)b * SS + k0 * 256) * 10;
#pragma unroll
      for (int i = 0; i < 10; ++i) st[t + i * 256] = src[t + i * 256];  // coalesced
      __syncthreads();
      const u32* row = st + t * 10;
      int tok = -1;
#pragma unroll
      for (int w = 0; w < 10; ++w) {
        u32 u = row[w];
        if (u & 0xFFFFu) tok = 2 * w;
        if (u >> 16)     tok = 2 * w + 1;
      }
      toks[b * SS + k0 * 256 + t] = (short)tok;
      cnt += (tok >= 0);
      __syncthreads();
    }
  } else {
    float4* st = (float4*)stage;
    for (int k0 = 0; k0 < 4; ++k0) {
      const float4* src = (const float4*)((const float*)in1 + ((size_t)b * SS + k0 * 256) * 20);
#pragma unroll
      for (int i = 0; i < 5; ++i) st[t + i * 256] = src[t + i * 256];  // coalesced 16B/lane
      __syncthreads();
      const float* row = stage + t * 20;
      int tok = -1;
#pragma unroll
      for (int w = 0; w < 20; ++w)
        if (row[w] != 0.f) tok = w;
      toks[b * SS + k0 * 256 + t] = (short)tok;
      cnt += (tok >= 0);
      __syncthreads();
    }
  }
  red[t] = cnt;
  __syncthreads();
  for (int stp = 128; stp > 0; stp >>= 1) {
    if (t < stp) red[t] += red[t + stp];
    __syncthreads();
  }
  if (t == 0) lens[b] = red[0];
}

// ---- BiLSTM via MFMA, 1 cell per lane: 256 blocks x 4 waves = all 1024 SIMDs ----
// Block = 4 batch-dirs. Every A-row l carries h[batch l>>2] (4x duplicated) -> D-row
// 4q+r = gates of batch q for all r; activation uses reg 0 only: 7 trans/step/SIMD.
// Wave w owns units 16w..16w+15, all 4 gate types in-lane (tiles tt). MFMA count/wave
// unchanged (12) -- the 4x row redundancy rides the idle matrix pipe.
// Weights prescaled: i,f,o rows by -log2e, g rows by +2log2e -> gates arrive as exp2 args.
__global__ __launch_bounds__(256)
void lstm_kernel(const void* Wih_f, const void* Whh_f, const void* b_f,
                 const void* Wih_b, const void* Whh_b, const void* b_b,
                 const int* mode_p, const short* toks, float* hout) {
  int bx = blockIdx.x;          // 0..255
  int dir = bx >> 7;
  int b0 = (bx & 127) * MB4;
  int t = threadIdx.x;
  int w = t >> 6, lane = t & 63, l = lane & 15, q = lane >> 4;
  int bsel = l >> 2;            // batch whose h this lane's A-row carries
  int mode = *mode_p;
  const void* Wih = dir ? Wih_b : Wih_f;
  const void* Whh = dir ? Whh_b : Whh_f;
  const void* bv  = dir ? b_b   : b_f;

  __shared__ __align__(16) f16 hbuf[2][MB4][PAD];  // [p][batch][unit(+pad)]
  __shared__ short tok_s[SS * MB4];                // [pos][m]

  for (int idx = t; idx < MB4 * SS; idx += 256) {
    int m = idx & 3, pos = idx >> 2;
    tok_s[pos * MB4 + m] = toks[(size_t)(b0 + m) * SS + pos];
  }
  for (int idx = t; idx < 2 * MB4 * PAD; idx += 256)
    ((f16*)hbuf)[idx] = (f16)0.f;

  // B fragments: n=lane&15 -> gate col (unit 16w+l, type tt), k=q*8+j.
  // kc0/1: W_hh; kc2: W_ih cols + bias at k=20. Prescale i,f,o: -log2e; g: +2log2e.
  f16x8 Bf[4][3];
#pragma unroll
  for (int tt = 0; tt < 4; ++tt) {
    float scl = (tt == 2) ? (2.f * LOG2E) : (-LOG2E);
    int g = 64 * tt + 16 * w + l;
#pragma unroll
    for (int kc = 0; kc < 2; ++kc) {
      f16x8 v;
#pragma unroll
      for (int j = 0; j < 8; ++j)
        v[j] = (f16)(scl * ldw(Whh, g * HH + kc * 32 + q * 8 + j, mode));
      Bf[tt][kc] = v;
    }
    f16x8 v2;
#pragma unroll
    for (int j = 0; j < 8; ++j) {
      int i = q * 8 + j;
      float f = 0.f;
      if (i < NI)       f = ldw(Wih, g * NI + i, mode);
      else if (i == NI) f = ldw(bv, g, mode);
      v2[j] = (f16)(scl * f);
    }
    Bf[tt][2] = v2;
  }
  __syncthreads();

  float c_st = 0.f, hlast = 0.f;
  int jj = 16 * w + l;
  const f32x4 z4 = {0.f, 0.f, 0.f, 0.f};

  // prologue: input projection (+bias) for s=0
  f32x4 accA[4];
  {
    int pos0 = dir ? (SS - 1) : 0;
    f16x8 a2 = onehot21((int)tok_s[pos0 * MB4 + bsel], q);
#pragma unroll
    for (int tt = 0; tt < 4; ++tt)
      accA[tt] = __builtin_amdgcn_mfma_f32_16x16x32_f16(a2, Bf[tt][2], z4, 0, 0, 0);
  }

#pragma unroll 2
  for (int s = 0; s < SS; ++s) {
    int p = s & 1;
    // critical path: h fragments; A[m=l][k=q*8+j] = h[bsel][k] (dup x4, broadcast reads)
    f16x8 a0 = *(const f16x8*)&hbuf[p][bsel][q * 8];
    f16x8 a1 = *(const f16x8*)&hbuf[p][bsel][32 + q * 8];
    // off-path: token for step s+1 (mask-wrapped; wrapped value unused)
    int posn = (dir ? (SS - 2 - s) : (s + 1)) & (SS - 1);
    int tkn = (int)tok_s[posn * MB4 + bsel];

    f32x4 acc[4];
#pragma unroll
    for (int tt = 0; tt < 4; ++tt)
      acc[tt] = __builtin_amdgcn_mfma_f32_16x16x32_f16(a0, Bf[tt][0], accA[tt], 0, 0, 0);
#pragma unroll
    for (int tt = 0; tt < 4; ++tt)
      acc[tt] = __builtin_amdgcn_mfma_f32_16x16x32_f16(a1, Bf[tt][1], acc[tt], 0, 0, 0);

    // off-path: input projection (+bias) for s+1
    {
      f16x8 a2 = onehot21(tkn, q);
#pragma unroll
      for (int tt = 0; tt < 4; ++tt)
        accA[tt] = __builtin_amdgcn_mfma_f32_16x16x32_f16(a2, Bf[tt][2], z4, 0, 0, 0);
    }

    // activation, reg 0 only: cell (batch q, unit jj). Ei=e^-i, Ef=e^-f, Eo=e^-o, G=e^2g:
    //   c' = [c(1+Ei)(G+1) + (G-1)(1+Ef)] / [(1+Ef)(1+Ei)(G+1)]
    //   C  = exp2(2*log2e*c');  h = (C-1)/[(1+Eo)(C+1)]
    {
      float Ei = fexp2(acc[0][0]);
      float Ef = fexp2(acc[1][0]);
      float G  = fexp2(acc[2][0]);
      float Eo = fexp2(acc[3][0]);
      float Ei1 = Ei + 1.f, Ef1 = Ef + 1.f, G1 = G + 1.f, Gm = G - 1.f;
      float t1 = Ei1 * G1;
      float num = fmaf(c_st, t1, Gm * Ef1);
      float cv = num * frcp(t1 * Ef1);
      c_st = cv;
      float C = fexp2((2.f * LOG2E) * cv);
      float hv = (C - 1.f) * frcp((Eo + 1.f) * (C + 1.f));
      hlast = hv;
      hbuf[p ^ 1][q][jj] = (f16)hv;
    }
    __syncthreads();
  }
  hout[(b0 + q) * 128 + dir * 64 + jj] = hlast;
}

// ---- conv path + FC head + softmax; 1 block = 1 batch, 256 threads ----
__global__ void head_kernel(const void* conv1_w, const void* conv2_w, const void* conv2_b,
                            const void* fc1_w, const void* fc1_b,
                            const void* fc2_w, const void* fc2_b,
                            const int* mode_p, const short* toks, const int* lens,
                            const float* hout, void* out) {
  int b = blockIdx.x;
  int t = threadIdx.x;  // 256 threads
  int mode = *mode_p;
  __shared__ float c1w[400];
  __shared__ short tok_s[SS];
  __shared__ float pav[2][80];
  __shared__ float avg[80];
  __shared__ float merged[228];
  __shared__ float fpart[4][64];
  __shared__ float fc1v[64];

  for (int i = t; i < 400; i += 256) c1w[i] = ldw(conv1_w, i, mode);
  for (int s = t; s < 256; s += 256) {}  // no-op keep structure
  for (int s = t; s < SS; s += 256) tok_s[s] = toks[b * SS + s];
  __syncthreads();

  int len = lens[b];
  int bw = len >> 2;
  if (t < 160) {
    int half = t / 80;
    int u = t - half * 80;
    int k = u / 20, cc = u % 20;
    int start = k * bw, mid = k * bw + (bw >> 1), end = (k + 1) * bw;
    int s0 = half ? mid : start;
    int s1 = half ? end : mid;
    float sum = 0.f;
    for (int s = s0; s < s1; ++s) {
      // faithful torch reshape: c1r[b,s,cc] lives at flat f = s*20+cc of the [20,1024] map
      int f = s * 20 + cc;
      int ch = f >> 10;
      int pos = f & 1023;
      int tk = tok_s[pos];
      if (tk >= 0) sum += c1w[ch * 20 + tk];  // pos >= len -> zero row -> contributes 0
    }
    pav[half][u] = sum;
  }
  __syncthreads();
  if (t < 80) avg[t] = (pav[0][t] + pav[1][t]) / (float)bw;
  __syncthreads();

  if (t < 128) merged[t] = hout[b * 128 + t];  // [h_fw | h_bw]
  if (t >= 128 && t < 228) {
    int o = t - 128;
    float dot = ldw(conv2_b, o, mode);
#pragma unroll
    for (int q = 0; q < 80; ++q)
      dot += avg[q] * ldw(conv2_w, o * 80 + q, mode);
    merged[t] = dot > 0.f ? dot : 0.f;  // relu
  }
  __syncthreads();

  // fc1: K-split 4 ways (228 = 4*57) across 256 threads
  {
    int o = t & 63, ch = t >> 6;
    float v = 0.f;
    int m0 = ch * 57, m1 = m0 + 57;
    for (int m = m0; m < m1; ++m)
      v += merged[m] * ldw(fc1_w, o * 228 + m, mode);
    fpart[ch][o] = v;
  }
  __syncthreads();
  if (t < 64)
    fc1v[t] = fpart[0][t] + fpart[1][t] + fpart[2][t] + fpart[3][t] + ldw(fc1_b, t, mode);
  __syncthreads();

  if (t == 0) {
    float x0 = ldw(fc2_b, 0, mode), x1 = ldw(fc2_b, 1, mode);
    for (int m = 0; m < 64; ++m) {
      x0 += fc1v[m] * ldw(fc2_w, m, mode);
      x1 += fc1v[m] * ldw(fc2_w, 64 + m, mode);
    }
    float mx = fmaxf(x0, x1);
    float e0 = fexp2(LOG2E * (x0 - mx)), e1 = fexp2(LOG2E * (x1 - mx));
    float inv = 1.f / (e0 + e1);
    if (mode) {
      ((__hip_bfloat16*)out)[b * 2 + 0] = __float2bfloat16(e0 * inv);
      ((__hip_bfloat16*)out)[b * 2 + 1] = __float2bfloat16(e1 * inv);
    } else {
      ((float*)out)[b * 2 + 0] = e0 * inv;
      ((float*)out)[b * 2 + 1] = e1 * inv;
    }
  }
}

extern "C" void kernel_launch(void* const* d_in, const int* in_sizes, int n_in,
                              void* d_out, int out_size, void* d_ws, size_t ws_size,
                              hipStream_t stream) {
  (void)in_sizes; (void)n_in; (void)out_size; (void)ws_size;
  char* ws = (char*)d_ws;
  int*   mode_p = (int*)ws;                                   // 4 B
  int*   lens   = (int*)(ws + 256);                           // 2 KB
  short* toks   = (short*)(ws + 256 + 2048);                  // 1 MB
  float* hout   = (float*)(ws + 256 + 2048 + (size_t)BB * SS * sizeof(short)); // 256 KB

  probe_kernel<<<1, 256, 0, stream>>>(d_in[3], mode_p);
  tok_kernel<<<BB, 256, 0, stream>>>(d_in[0], mode_p, toks, lens);
  lstm_kernel<<<256, 256, 0, stream>>>(d_in[1], d_in[2], d_in[3],
                                       d_in[4], d_in[5], d_in[6],
                                       mode_p, toks, hout);
  head_kernel<<<BB, 256, 0, stream>>>(d_in[7], d_in[8], d_in[9],
                                      d_in[10], d_in[11], d_in[12], d_in[13],
                                      mode_p, toks, lens, hout, d_out);
}

// Round 7
// 423.502 us; speedup vs baseline: 2.6439x; 1.1245x over previous
//
#include <hip/hip_runtime.h>
#include <hip/hip_bf16.h>

#define BB 512
#define SS 1024
#define NI 20
#define HH 64
#define NG 256   // 4*H
#define MB4 4    // batch-dirs per block (1 cell per lane)
#define PAD 72
#define TSTR 257 // table row stride (floats): breaks 4-way bank aliasing

typedef unsigned short u16;
typedef unsigned int u32;
typedef unsigned long long u64;
typedef _Float16 f16;
typedef f16 f16x8 __attribute__((ext_vector_type(8)));
typedef float f32x4 __attribute__((ext_vector_type(4)));

#define LOG2E 1.4426950408889634f

__device__ __forceinline__ float bf2f(u16 b) { return __uint_as_float(((u32)b) << 16); }
// mode==1: data is bf16; mode==0: data is fp32
__device__ __forceinline__ float ldw(const void* p, int idx, int mode) {
  return mode ? bf2f(((const u16*)p)[idx]) : ((const float*)p)[idx];
}
__device__ __forceinline__ float frcp(float x) { return __builtin_amdgcn_rcpf(x); }
__device__ __forceinline__ float fexp2(float x) { return __builtin_amdgcn_exp2f(x); }

// ---- BiLSTM, fully fused: mode probe + token extraction + MFMA recurrence ----
// 256 blocks x 256 thr = 1 block/CU, 1 wave/SIMD. Block = (dir, 4 batches).
// Wave w owns units 16w..16w+15, all 4 gate types in-lane; lane (l,q) = cell
// (batch q, unit 16w+l). A-rows duplicate h[batch l>>2] 4x. Input projection
// rides the MFMA C-init from an LDS table (21 toks x 256 gates, prescaled),
// prefetched one step ahead -> only 8 MFMA/step (2 K-chunks x 4 gate types).
// Weights prescaled: i,f,o rows by -log2e, g rows by +2log2e (exp2-ready gates).
__global__ __launch_bounds__(256)
void lstm_kernel(const void* in1,
                 const void* Wih_f, const void* Whh_f, const void* b_f,
                 const void* Wih_b, const void* Whh_b, const void* b_b,
                 short* toks_g, int* lens, float* hout) {
  int bx = blockIdx.x;          // 0..255
  int dir = bx >> 7;
  int b0 = (bx & 127) * MB4;
  int t = threadIdx.x;
  int w = t >> 6, lane = t & 63, l = lane & 15, q = lane >> 4;
  int bsel = l >> 2;            // batch whose h this lane's A-row carries

  __shared__ __align__(16) float table[21 * TSTR];  // 21.1 KB; doubles as extract staging
  __shared__ __align__(16) f16 hbuf[2][MB4][PAD];
  __shared__ short tok_s[SS * MB4];                 // [pos][m], stores tok+1
  __shared__ u64 red[256];
  __shared__ int mode_sh;

  // ---- mode probe (redundant per block): b_f read as bf16; fp32 shows wild exponents ----
  if (t == 0) mode_sh = 1;
  __syncthreads();
  {
    float v = bf2f(((const u16*)b_f)[t]);
    if (!(fabsf(v) < 1000.0f)) atomicAnd(&mode_sh, 0);
  }
  __syncthreads();
  int mode = mode_sh;
  const void* Wih = dir ? Wih_b : Wih_f;
  const void* Whh = dir ? Whh_b : Whh_f;
  const void* bv  = dir ? b_b   : b_f;

  // ---- token extraction for this block's 4 batches (staged through `table` memory) ----
  u64 cnt = 0;  // packed 4x16-bit valid counts
  for (int m = 0; m < MB4; ++m) {
    if (mode) {
      u32* st = (u32*)table;
      for (int k0 = 0; k0 < 4; ++k0) {
        const u32* src = (const u32*)in1 + ((size_t)(b0 + m) * SS + k0 * 256) * 10;
#pragma unroll
        for (int i = 0; i < 10; ++i) st[t + i * 256] = src[t + i * 256];  // coalesced
        __syncthreads();
        const u32* row = st + t * 10;
        int tok = -1;
#pragma unroll
        for (int ww = 0; ww < 10; ++ww) {
          u32 u = row[ww];
          if (u & 0xFFFFu) tok = 2 * ww;
          if (u >> 16)     tok = 2 * ww + 1;
        }
        tok_s[(k0 * 256 + t) * MB4 + m] = (short)(tok + 1);
        if (dir == 0) toks_g[(size_t)(b0 + m) * SS + k0 * 256 + t] = (short)tok;
        cnt += (u64)(tok >= 0) << (16 * m);
        __syncthreads();
      }
    } else {
      float4* st = (float4*)table;
      for (int k0 = 0; k0 < 4; ++k0) {
        const float4* src = (const float4*)((const float*)in1 + ((size_t)(b0 + m) * SS + k0 * 256) * 20);
#pragma unroll
        for (int i = 0; i < 5; ++i) st[t + i * 256] = src[t + i * 256];  // coalesced 16B/lane
        __syncthreads();
        const float* row = (const float*)table + t * 20;
        int tok = -1;
#pragma unroll
        for (int ww = 0; ww < 20; ++ww)
          if (row[ww] != 0.f) tok = ww;
        tok_s[(k0 * 256 + t) * MB4 + m] = (short)(tok + 1);
        if (dir == 0) toks_g[(size_t)(b0 + m) * SS + k0 * 256 + t] = (short)tok;
        cnt += (u64)(tok >= 0) << (16 * m);
        __syncthreads();
      }
    }
  }
  // lens: packed u64 tree reduction (fwd blocks export)
  red[t] = cnt;
  __syncthreads();
  for (int stp = 128; stp > 0; stp >>= 1) {
    if (t < stp) red[t] += red[t + stp];
    __syncthreads();
  }
  if (dir == 0 && t < MB4)
    lens[b0 + t] = (int)((red[0] >> (16 * t)) & 0xFFFFull);
  __syncthreads();

  // ---- build x-projection table: table[tok+1][g] = scl_g * (W_ih[g][tok] + b[g]); row 0 = bias ----
  for (int idx = t; idx < 21 * 256; idx += 256) {
    int r = idx >> 8, g = idx & 255;
    float scl = ((g >> 6) == 2) ? (2.f * LOG2E) : (-LOG2E);
    float v = ldw(bv, g, mode);
    if (r > 0) v += ldw(Wih, g * NI + (r - 1), mode);
    table[r * TSTR + g] = scl * v;
  }
  // ---- W_hh B-fragments: n=lane&15 -> gate col (unit 16w+l, type tt), k=q*8+j ----
  f16x8 Bf[4][2];
#pragma unroll
  for (int tt = 0; tt < 4; ++tt) {
    float scl = (tt == 2) ? (2.f * LOG2E) : (-LOG2E);
    int g = 64 * tt + 16 * w + l;
#pragma unroll
    for (int kc = 0; kc < 2; ++kc) {
      f16x8 v;
#pragma unroll
      for (int j = 0; j < 8; ++j)
        v[j] = (f16)(scl * ldw(Whh, g * HH + kc * 32 + q * 8 + j, mode));
      Bf[tt][kc] = v;
    }
  }
  for (int idx = t; idx < 2 * MB4 * PAD; idx += 256)
    ((f16*)hbuf)[idx] = (f16)0.f;
  __syncthreads();

  float c_st = 0.f, hlast = 0.f;
  int jj = 16 * w + l;
  int tbase = 16 * w + l;  // gate column offset within a table row

  // x-pipeline prologue: wx for s=0 (in regs), tok for s=1 (in reg)
  float wxc[4];
  {
    int pos0 = dir ? (SS - 1) : 0;
    int base = (int)tok_s[pos0 * MB4 + q] * TSTR + tbase;
    wxc[0] = table[base];       wxc[1] = table[base + 64];
    wxc[2] = table[base + 128]; wxc[3] = table[base + 192];
  }
  int tok1;
  {
    int pos1 = dir ? (SS - 2) : 1;
    tok1 = (int)tok_s[pos1 * MB4 + q];
  }

#pragma unroll 2
  for (int s = 0; s < SS; ++s) {
    int p = s & 1;
    // critical path: h fragments (A[m=l][k=q*8+j] = h[bsel][k], 4x dup rows)
    f16x8 a0 = *(const f16x8*)&hbuf[p][bsel][q * 8];
    f16x8 a1 = *(const f16x8*)&hbuf[p][bsel][32 + q * 8];
    // off-path: wx prefetch for s+1 (tok1 from pipeline), tok fetch for s+2
    float wxn[4];
    {
      int base = tok1 * TSTR + tbase;
      wxn[0] = table[base];       wxn[1] = table[base + 64];
      wxn[2] = table[base + 128]; wxn[3] = table[base + 192];
    }
    {
      int pos2 = (dir ? (SS - 3 - s) : (s + 2)) & (SS - 1);  // wrapped values unused
      tok1 = (int)tok_s[pos2 * MB4 + q];
    }

    f32x4 acc[4];
#pragma unroll
    for (int tt = 0; tt < 4; ++tt) {
      f32x4 ci = {wxc[tt], wxc[tt], wxc[tt], wxc[tt]};  // C-init = x-projection (+bias)
      acc[tt] = __builtin_amdgcn_mfma_f32_16x16x32_f16(a0, Bf[tt][0], ci, 0, 0, 0);
    }
#pragma unroll
    for (int tt = 0; tt < 4; ++tt)
      acc[tt] = __builtin_amdgcn_mfma_f32_16x16x32_f16(a1, Bf[tt][1], acc[tt], 0, 0, 0);

    // activation (verified r6): Ei=e^-i, Ef=e^-f, Eo=e^-o, G=e^2g
    {
      float Ei = fexp2(acc[0][0]);
      float Ef = fexp2(acc[1][0]);
      float G  = fexp2(acc[2][0]);
      float Eo = fexp2(acc[3][0]);
      float Ei1 = Ei + 1.f, Ef1 = Ef + 1.f, G1 = G + 1.f, Gm = G - 1.f;
      float t1 = Ei1 * G1;
      float num = fmaf(c_st, t1, Gm * Ef1);
      float cv = num * frcp(t1 * Ef1);
      c_st = cv;
      float C = fexp2((2.f * LOG2E) * cv);
      float hv = (C - 1.f) * frcp((Eo + 1.f) * (C + 1.f));
      hlast = hv;
      hbuf[p ^ 1][q][jj] = (f16)hv;
    }
    __syncthreads();
    wxc[0] = wxn[0]; wxc[1] = wxn[1]; wxc[2] = wxn[2]; wxc[3] = wxn[3];
  }
  hout[(b0 + q) * 128 + dir * 64 + jj] = hlast;
}

// ---- conv path + FC head + softmax; 1 block = 1 batch, 256 threads ----
__global__ void head_kernel(const void* conv1_w, const void* conv2_w, const void* conv2_b,
                            const void* fc1_w, const void* fc1_b,
                            const void* fc2_w, const void* fc2_b,
                            const void* bvec, const short* toks, const int* lens,
                            const float* hout, void* out) {
  int b = blockIdx.x;
  int t = threadIdx.x;  // 256 threads
  __shared__ float c1w[400];
  __shared__ short tok_s[SS];
  __shared__ float pav[2][80];
  __shared__ float avg[80];
  __shared__ float merged[228];
  __shared__ float fpart[4][64];
  __shared__ float fc1v[64];
  __shared__ int mode_sh;

  if (t == 0) mode_sh = 1;
  __syncthreads();
  {
    float v = bf2f(((const u16*)bvec)[t]);
    if (!(fabsf(v) < 1000.0f)) atomicAnd(&mode_sh, 0);
  }
  __syncthreads();
  int mode = mode_sh;

  for (int i = t; i < 400; i += 256) c1w[i] = ldw(conv1_w, i, mode);
  for (int s = t; s < SS; s += 256) tok_s[s] = toks[(size_t)b * SS + s];
  __syncthreads();

  int len = lens[b];
  int bw = len >> 2;
  if (t < 160) {
    int half = t / 80;
    int u = t - half * 80;
    int k = u / 20, cc = u % 20;
    int start = k * bw, mid = k * bw + (bw >> 1), end = (k + 1) * bw;
    int s0 = half ? mid : start;
    int s1 = half ? end : mid;
    float sum = 0.f;
    for (int s = s0; s < s1; ++s) {
      // faithful torch reshape: c1r[b,s,cc] lives at flat f = s*20+cc of the [20,1024] map
      int f = s * 20 + cc;
      int ch = f >> 10;
      int pos = f & 1023;
      int tk = tok_s[pos];
      if (tk >= 0) sum += c1w[ch * 20 + tk];  // pos >= len -> zero row -> contributes 0
    }
    pav[half][u] = sum;
  }
  __syncthreads();
  if (t < 80) avg[t] = (pav[0][t] + pav[1][t]) / (float)bw;
  __syncthreads();

  if (t < 128) merged[t] = hout[b * 128 + t];  // [h_fw | h_bw]
  if (t >= 128 && t < 228) {
    int o = t - 128;
    float dot = ldw(conv2_b, o, mode);
#pragma unroll
    for (int q = 0; q < 80; ++q)
      dot += avg[q] * ldw(conv2_w, o * 80 + q, mode);
    merged[t] = dot > 0.f ? dot : 0.f;  // relu
  }
  __syncthreads();

  // fc1: K-split 4 ways (228 = 4*57) across 256 threads
  {
    int o = t & 63, ch = t >> 6;
    float v = 0.f;
    int m0 = ch * 57, m1 = m0 + 57;
    for (int m = m0; m < m1; ++m)
      v += merged[m] * ldw(fc1_w, o * 228 + m, mode);
    fpart[ch][o] = v;
  }
  __syncthreads();
  if (t < 64)
    fc1v[t] = fpart[0][t] + fpart[1][t] + fpart[2][t] + fpart[3][t] + ldw(fc1_b, t, mode);
  __syncthreads();

  if (t == 0) {
    float x0 = ldw(fc2_b, 0, mode), x1 = ldw(fc2_b, 1, mode);
    for (int m = 0; m < 64; ++m) {
      x0 += fc1v[m] * ldw(fc2_w, m, mode);
      x1 += fc1v[m] * ldw(fc2_w, 64 + m, mode);
    }
    float mx = fmaxf(x0, x1);
    float e0 = fexp2(LOG2E * (x0 - mx)), e1 = fexp2(LOG2E * (x1 - mx));
    float inv = 1.f / (e0 + e1);
    if (mode) {
      ((__hip_bfloat16*)out)[b * 2 + 0] = __float2bfloat16(e0 * inv);
      ((__hip_bfloat16*)out)[b * 2 + 1] = __float2bfloat16(e1 * inv);
    } else {
      ((float*)out)[b * 2 + 0] = e0 * inv;
      ((float*)out)[b * 2 + 1] = e1 * inv;
    }
  }
}

extern "C" void kernel_launch(void* const* d_in, const int* in_sizes, int n_in,
                              void* d_out, int out_size, void* d_ws, size_t ws_size,
                              hipStream_t stream) {
  (void)in_sizes; (void)n_in; (void)out_size; (void)ws_size;
  char* ws = (char*)d_ws;
  int*   lens = (int*)(ws + 256);                             // 2 KB
  short* toks = (short*)(ws + 256 + 2048);                    // 1 MB
  float* hout = (float*)(ws + 256 + 2048 + (size_t)BB * SS * sizeof(short)); // 256 KB

  lstm_kernel<<<256, 256, 0, stream>>>(d_in[0],
                                       d_in[1], d_in[2], d_in[3],
                                       d_in[4], d_in[5], d_in[6],
                                       toks, lens, hout);
  head_kernel<<<BB, 256, 0, stream>>>(d_in[7], d_in[8], d_in[9],
                                      d_in[10], d_in[11], d_in[12], d_in[13],
                                      d_in[3], toks, lens, hout, d_out);
}